// Round 9
// baseline (186.787 us; speedup 1.0000x reference)
//
#include <hip/hip_runtime.h>
#include <math.h>

#define EPS_F 1e-6f

typedef __attribute__((ext_vector_type(8))) short bf16x8;
typedef __attribute__((ext_vector_type(4))) float f32x4;

// ---- workspace layout (float offsets) ----
#define OFF_BV  0                            // folded v bias [256]
#define OFF_VC  (OFF_BV + 256)               // dwconv output [256][4096]
#define OFF_PS  (OFF_VC + 256*4096)          // (unused, kept for layout stability)
#define OFF_PSV (OFF_PS + 8*128*4096)
#define OFF_SM  (OFF_PSV + 8*128*64)         // Sm [8][64*64] (atomic accum)
#define OFF_SV  (OFF_SM + 8*4096)            // sv [8][64]   (atomic accum)
#define OFF_QF  (OFF_SV + 512)               // qf [512 row=h*64+a][4096 n] fp32
#define OFF_WQH (OFF_QF + 512*4096)          // folded Wq hi bf16 [256][256] (ushort)
#define OFF_WQL (OFF_WQH + 32768)
#define OFF_WKH (OFF_WQL + 32768)
#define OFF_WKL (OFF_WKH + 32768)
#define OFF_XTH (OFF_WKL + 32768)            // X^T hi bf16 [4096 tok][256 c] (ushort)
#define OFF_XTL (OFF_XTH + 524288)

__device__ __forceinline__ void split_bf16(float v, unsigned short& h, unsigned short& l) {
    unsigned int b = __float_as_uint(v);
    h = (unsigned short)(b >> 16);
    float fh = __uint_as_float(b & 0xFFFF0000u);
    l = (unsigned short)(__float_as_uint(v - fh) >> 16);
}

// Prologue, 4738 blocks x 256 threads, full parallelism per job:
//   b <  4096: dwconv, 1 output/thread (c = b>>4, n = (b&15)*256+t)
//   b <  4352: weight fold (row b-4096)
//   b <  4608: X transpose/split (tile b-4352)
//   b <  4738: zero Sm/sv accumulators (for k_fused atomics)
__global__ __launch_bounds__(256) void k_pre(
    const float* __restrict__ x,
    const float* __restrict__ Wq, const float* __restrict__ Wk,
    const float* __restrict__ Wv, const float* __restrict__ bv,
    const float* __restrict__ Wmq, const float* __restrict__ Wmk,
    const float* __restrict__ Wmv, const float* __restrict__ bmv,
    float* __restrict__ ws)
{
    __shared__ float Ts[64][65];
    int b = blockIdx.x, t = threadIdx.x;
    if (b < 4096) {
        int c = b >> 4;
        int n = (b & 15) * 256 + t;
        int z = n >> 8, y = (n >> 4) & 15, xx = n & 15;
        const float* xc = x + c * 4096;
        const float* wc = Wv + c * 27;
        float acc = 0.f;
        #pragma unroll
        for (int kz = 0; kz < 3; ++kz) {
            int zz = z + kz - 1;
            if (zz < 0 || zz > 15) continue;
            #pragma unroll
            for (int ky = 0; ky < 3; ++ky) {
                int yy = y + ky - 1;
                if (yy < 0 || yy > 15) continue;
                #pragma unroll
                for (int kx = 0; kx < 3; ++kx) {
                    int xv = xx + kx - 1;
                    if (xv < 0 || xv > 15) continue;
                    acc = fmaf(wc[(kz*3 + ky)*3 + kx], xc[(zz << 8) + (yy << 4) + xv], acc);
                }
            }
        }
        ws[OFF_VC + (size_t)c*4096 + n] = acc;
    } else if (b < 4352) {
        int row = b - 4096, c = t;
        int h = row >> 6, e = row & 63;
        float aq = 0.f, ak = 0.f;
        for (int d = 0; d < 64; ++d) {
            float mq = Wmq[e*64 + d];
            float mk = Wmk[e*64 + d];
            int src = (h*64 + d)*256 + c;
            aq = fmaf(mq, Wq[src], aq);
            ak = fmaf(mk, Wk[src], ak);
        }
        unsigned short hh, ll;
        unsigned short* WQH = (unsigned short*)(ws + OFF_WQH);
        unsigned short* WQL = (unsigned short*)(ws + OFF_WQL);
        unsigned short* WKH = (unsigned short*)(ws + OFF_WKH);
        unsigned short* WKL = (unsigned short*)(ws + OFF_WKL);
        split_bf16(aq, hh, ll); WQH[row*256 + c] = hh; WQL[row*256 + c] = ll;
        split_bf16(ak, hh, ll); WKH[row*256 + c] = hh; WKL[row*256 + c] = ll;
        if (c == 0) {
            float av = 0.f;
            for (int d = 0; d < 64; ++d) av = fmaf(Wmv[e*64 + d], bv[h*64 + d], av);
            ws[OFF_BV + row] = av + bmv[e];
        }
    } else if (b < 4608) {
        int bx = b - 4352;
        int tx = bx & 63, cy = bx >> 6;
        int lr = t >> 6, lc2 = t & 63;
        #pragma unroll
        for (int i = 0; i < 16; ++i) {
            int row = lr*16 + i;
            Ts[row][lc2] = x[(size_t)(cy*64 + row)*4096 + tx*64 + lc2];
        }
        __syncthreads();
        int tok = t >> 2, c16 = (t & 3) * 16;
        unsigned int hw[8], lw[8];
        #pragma unroll
        for (int j = 0; j < 8; ++j) {
            float v0 = Ts[c16 + 2*j][tok], v1 = Ts[c16 + 2*j + 1][tok];
            unsigned int b0 = __float_as_uint(v0), b1 = __float_as_uint(v1);
            hw[j] = (b0 >> 16) | (b1 & 0xFFFF0000u);
            float f0 = __uint_as_float(b0 & 0xFFFF0000u);
            float f1 = __uint_as_float(b1 & 0xFFFF0000u);
            lw[j] = (__float_as_uint(v0 - f0) >> 16) | (__float_as_uint(v1 - f1) & 0xFFFF0000u);
        }
        unsigned short* XH = (unsigned short*)(ws + OFF_XTH);
        unsigned short* XL = (unsigned short*)(ws + OFF_XTL);
        size_t base = (size_t)(tx*64 + tok)*256 + cy*64 + c16;
        uint4 H0 = {hw[0], hw[1], hw[2], hw[3]}, H1 = {hw[4], hw[5], hw[6], hw[7]};
        uint4 L0 = {lw[0], lw[1], lw[2], lw[3]}, L1 = {lw[4], lw[5], lw[6], lw[7]};
        *(uint4*)(XH + base) = H0;  *(uint4*)(XH + base + 8) = H1;
        *(uint4*)(XL + base) = L0;  *(uint4*)(XL + base + 8) = L1;
    } else {
        int idx = (b - 4608)*256 + t;        // 0..33279
        if (idx < 32768) ws[OFF_SM + idx] = 0.f;
        else             ws[OFF_SV + idx - 32768] = 0.f;
    }
}

// 512 threads / 8 waves, 32-token chunks -> grid (128,4) = 512 blocks = 2 blocks/CU.
// Waves: kq=w>>2 (K/Q), mh=w&1 (token 16-half), nh=(w>>1)&1 (feat 32-half);
// per wave 1 M-tile x 2 N-tiles of 16x16, K=256 via 4 slabs x 2 ks, 3 mfma each.
// Tail: Q dumps partials to LDS, K adds and atomicAdds into global Sm/sv.
__global__ __launch_bounds__(512, 4) void k_fused(
    const float* __restrict__ bmk, const float* __restrict__ bmq,
    const float* __restrict__ Wmv, float* __restrict__ ws)
{
    __shared__ float smem[16384];   // 64 KB
    unsigned short* su = (unsigned short*)smem;

    int t = threadIdx.x;
    int chunk = blockIdx.x;       // 0..127
    int hb = blockIdx.y;          // 0..3
    int n0 = chunk * 32;
    int w = t >> 6, lane = t & 63;
    int kq = w >> 2;              // 0 = K waves, 1 = Q waves
    int wi = w & 3;
    int mh = wi & 1, nh = wi >> 1;
    int l15 = lane & 15, l4 = lane >> 4;
    bool isQ = (t >= 256);
    int tl = t & 255;

    const unsigned short* XH  = (const unsigned short*)(ws + OFF_XTH);
    const unsigned short* XL  = (const unsigned short*)(ws + OFF_XTL);
    const unsigned short* WKHp = (const unsigned short*)(ws + OFF_WKH);
    const unsigned short* WKLp = (const unsigned short*)(ws + OFF_WKL);
    const unsigned short* WQHp = (const unsigned short*)(ws + OFF_WQH);
    const unsigned short* WQLp = (const unsigned short*)(ws + OFF_WQL);

    f32x4 acc[2];
    acc[0] = (f32x4){0.f, 0.f, 0.f, 0.f};
    acc[1] = (f32x4){0.f, 0.f, 0.f, 0.f};
    float accV[2][4];
    #pragma unroll
    for (int i = 0; i < 2; ++i)
        #pragma unroll
        for (int j = 0; j < 4; ++j) accV[i][j] = 0.f;

    // ---- phase 1: K & Q projection GEMMs via MFMA, 4 slabs of K=64 ----
    for (int cs = 0; cs < 4; ++cs) {
        int c0 = cs * 64;
        {   // X: 2 bufs x 32 rows x 8 slots; W: 4 bufs x 64 rows x 8 slots
            int s = t & 7;
            int xb = t >> 8;                      // 0=hi 1=lo
            int r5 = (t >> 3) & 31;
            const unsigned short* XSrc = xb ? XL : XH;
            unsigned short* xd = su + xb*2048 + r5*64 + (((s) ^ (r5 & 7)) << 3);
            *(uint4*)xd = *(const uint4*)(XSrc + (size_t)(n0 + r5)*256 + c0 + s*8);
            int r6 = (t >> 3) & 63;
            size_t wo = (size_t)(hb*64 + r6)*256 + c0 + s*8;
            unsigned short* wd0 = su + 4096 + r6*64 + (((s) ^ (r6 & 7)) << 3);
            *(uint4*)(wd0)          = *(const uint4*)(WKHp + wo);
            *(uint4*)(wd0 + 4096)   = *(const uint4*)(WKLp + wo);
            *(uint4*)(wd0 + 8192)   = *(const uint4*)(WQHp + wo);
            *(uint4*)(wd0 + 12288)  = *(const uint4*)(WQLp + wo);
        }
        __syncthreads();
        const unsigned short* Xh = su;
        const unsigned short* Xl = su + 2048;
        const unsigned short* Wh = su + 4096 + kq*8192;
        const unsigned short* Wl = Wh + 4096;
        #pragma unroll
        for (int ks = 0; ks < 2; ++ks) {
            int ar = mh*16 + l15;
            int aoff = ar*64 + (((ks*4 + l4) ^ (ar & 7)) << 3);
            bf16x8 ah = *(const bf16x8*)(Xh + aoff);
            bf16x8 al = *(const bf16x8*)(Xl + aoff);
            #pragma unroll
            for (int nt = 0; nt < 2; ++nt) {
                int br = nh*32 + nt*16 + l15;
                int boff = br*64 + (((ks*4 + l4) ^ (br & 7)) << 3);
                bf16x8 bh = *(const bf16x8*)(Wh + boff);
                bf16x8 bl = *(const bf16x8*)(Wl + boff);
                acc[nt] = __builtin_amdgcn_mfma_f32_16x16x32_bf16(ah, bh, acc[nt], 0, 0, 0);
                acc[nt] = __builtin_amdgcn_mfma_f32_16x16x32_bf16(al, bh, acc[nt], 0, 0, 0);
                acc[nt] = __builtin_amdgcn_mfma_f32_16x16x32_bf16(ah, bl, acc[nt], 0, 0, 0);
            }
        }
        __syncthreads();
    }

    // ---- K waves stage V tiles: Vs[64 d][32 tok] @8192, Wmv_s[64][68] @10240 ----
    float* Vs = smem + 8192;
    float* Wms = smem + 10240;
    if (!isQ) {
        const float* vcb = ws + OFF_VC + (size_t)hb*64*4096;
        #pragma unroll
        for (int i = 0; i < 8; ++i) {
            int idx = i*256 + tl;           // 0..2047
            int row = idx >> 5, col = idx & 31;
            Vs[row*32 + col] = vcb[(size_t)row*4096 + n0 + col];
        }
        #pragma unroll
        for (int i = 0; i < 16; ++i) { int idx = i*256 + tl; Wms[(idx & 63)*68 + (idx >> 6)] = Wmv[idx]; }
    }
    __syncthreads();

    // ---- V-projection GEMM (K waves, scalar, K=64), tile [2 tok][4 e] ----
    int n2 = (tl >> 4) * 2;
    int e4 = (tl & 15) * 4;
    if (!isQ) {
        #pragma unroll 4
        for (int d = 0; d < 64; ++d) {
            float x0 = Vs[d*32 + n2], x1 = Vs[d*32 + n2 + 1];
            float4 wv4 = *(const float4*)&Wms[d*68 + e4];
            float wv[4] = {wv4.x, wv4.y, wv4.z, wv4.w};
            #pragma unroll
            for (int jj = 0; jj < 4; ++jj) {
                accV[0][jj] = fmaf(x0, wv[jj], accV[0][jj]);
                accV[1][jj] = fmaf(x1, wv[jj], accV[1][jj]);
            }
        }
    }
    __syncthreads();

    // ---- phase 2: K waves write kf (MFMA frags) and vf (scalar) ----
    float* kfp = smem;          // [32][64]
    float* kfm = smem + 2048;
    float* vfp = smem + 4096;
    float* vfm = smem + 6144;
    if (!isQ) {
        float bk0 = bmk[nh*32 + l15], bk1 = bmk[nh*32 + 16 + l15];
        #pragma unroll
        for (int nt = 0; nt < 2; ++nt) {
            float bkv = nt ? bk1 : bk0;
            int feat = nh*32 + nt*16 + l15;
            #pragma unroll
            for (int r = 0; r < 4; ++r) {
                int tok = mh*16 + l4*4 + r;
                float v = acc[nt][r] + bkv;
                kfp[tok*64 + feat] = __expf(v);
                kfm[tok*64 + feat] = __expf(-v);
            }
        }
        float bvv[4];
        #pragma unroll
        for (int j = 0; j < 4; ++j) bvv[j] = ws[OFF_BV + hb*64 + e4 + j];
        #pragma unroll
        for (int ii = 0; ii < 2; ++ii) {
            float pv[4], mv[4];
            #pragma unroll
            for (int jj = 0; jj < 4; ++jj) {
                float bb = accV[ii][jj] + bvv[jj];
                pv[jj] = __expf(bb);  mv[jj] = __expf(-bb);
            }
            *(float4*)&vfp[(n2 + ii)*64 + e4] = make_float4(pv[0], pv[1], pv[2], pv[3]);
            *(float4*)&vfm[(n2 + ii)*64 + e4] = make_float4(mv[0], mv[1], mv[2], mv[3]);
        }
    }
    __syncthreads();

    // ---- phase 3: outer products over 16 tokens per group ----
    float aSp[4][4], aSm[4][4], svp[4], svm[4];
    #pragma unroll
    for (int i = 0; i < 4; ++i) {
        svp[i] = 0.f; svm[i] = 0.f;
        #pragma unroll
        for (int j = 0; j < 4; ++j) { aSp[i][j] = 0.f; aSm[i][j] = 0.f; }
    }
    int a4 = (tl & 15) * 4, f4 = (tl >> 4) * 4;
    int nb = isQ ? 16 : 0;
    #pragma unroll 2
    for (int nn = 0; nn < 16; ++nn) {
        int n = nb + nn;
        float4 kp4 = *(const float4*)&kfp[n*64 + a4];
        float4 km4 = *(const float4*)&kfm[n*64 + a4];
        float4 vp4 = *(const float4*)&vfp[n*64 + f4];
        float4 vm4 = *(const float4*)&vfm[n*64 + f4];
        float kp[4] = {kp4.x, kp4.y, kp4.z, kp4.w};
        float km[4] = {km4.x, km4.y, km4.z, km4.w};
        float vp[4] = {vp4.x, vp4.y, vp4.z, vp4.w};
        float vm[4] = {vm4.x, vm4.y, vm4.z, vm4.w};
        #pragma unroll
        for (int ai = 0; ai < 4; ++ai) {
            svp[ai] += kp[ai];  svm[ai] += km[ai];
            #pragma unroll
            for (int fi = 0; fi < 4; ++fi) {
                aSp[ai][fi] = fmaf(kp[ai], vp[fi], aSp[ai][fi]);
                aSm[ai][fi] = fmaf(km[ai], vm[fi], aSm[ai][fi]);
            }
        }
    }
    __syncthreads();

    // ---- exchange: Q dumps partials, K adds and atomicAdds into Sm/sv ----
    if (isQ) {
        #pragma unroll
        for (int i = 0; i < 4; ++i)
            #pragma unroll
            for (int j = 0; j < 4; ++j) {
                smem[(i*4 + j)*256 + tl]      = aSp[i][j];
                smem[(16 + i*4 + j)*256 + tl] = aSm[i][j];
            }
        if (tl < 16) {
            #pragma unroll
            for (int i = 0; i < 4; ++i) {
                smem[8192 + i*16 + tl]      = svp[i];
                smem[8192 + 64 + i*16 + tl] = svm[i];
            }
        }
    }
    __syncthreads();
    if (!isQ) {
        #pragma unroll
        for (int i = 0; i < 4; ++i)
            #pragma unroll
            for (int j = 0; j < 4; ++j) {
                aSp[i][j] += smem[(i*4 + j)*256 + tl];
                aSm[i][j] += smem[(16 + i*4 + j)*256 + tl];
            }
        float* gSp = ws + OFF_SM + (size_t)hb*4096;
        float* gSm2 = ws + OFF_SM + (size_t)(hb + 4)*4096;
        #pragma unroll
        for (int ai = 0; ai < 4; ++ai)
            #pragma unroll
            for (int fi = 0; fi < 4; ++fi) {
                atomicAdd(&gSp[(a4 + ai)*64 + f4 + fi], aSp[ai][fi]);
                atomicAdd(&gSm2[(a4 + ai)*64 + f4 + fi], aSm[ai][fi]);
            }
        if (tl < 16) {
            #pragma unroll
            for (int i = 0; i < 4; ++i) {
                svp[i] += smem[8192 + i*16 + tl];
                svm[i] += smem[8192 + 64 + i*16 + tl];
                atomicAdd(&ws[OFF_SV + hb*64 + a4 + i], svp[i]);
                atomicAdd(&ws[OFF_SV + (hb + 4)*64 + a4 + i], svm[i]);
            }
        }
    }
    __syncthreads();

    // ---- Q waves: exp(+-q) -> LDS transpose qT[feat][tok] (stride 36) ----
    float* qTp = smem;              // 64*36
    float* qTm = smem + 2304;
    if (isQ) {
        float bq0 = bmq[nh*32 + l15], bq1 = bmq[nh*32 + 16 + l15];
        #pragma unroll
        for (int nt = 0; nt < 2; ++nt) {
            float bqv = nt ? bq1 : bq0;
            int feat = nh*32 + nt*16 + l15;
            #pragma unroll
            for (int r = 0; r < 4; ++r) {
                int tok = mh*16 + l4*4 + r;
                float v = acc[nt][r] + bqv;
                qTp[feat*36 + tok] = __expf(v);
                qTm[feat*36 + tok] = __expf(-v);
            }
        }
    }
    __syncthreads();
    // ---- all threads: copy qT -> global qf (feature-major layout) ----
    float* gq = ws + OFF_QF;
    #pragma unroll
    for (int j = 0; j < 2; ++j) {
        int un = t + 512*j;               // 0..1023
        int s = un >> 9;
        int rem = un & 511;
        int feat = rem >> 3, t4 = (rem & 7) * 4;
        const float* src = (s ? &qTm[feat*36 + t4] : &qTp[feat*36 + t4]);
        float4 v = *(const float4*)src;
        *(float4*)&gq[(size_t)((hb + 4*s)*64 + feat)*4096 + n0 + t4] = v;
    }
}

// Per (h 0..7, chunk32 0..127): out = (qf.Sm)/(qf.sv+eps). 1024 blocks -> 4/CU.
__global__ __launch_bounds__(256, 4) void k_out(
    const float* __restrict__ ws, float* __restrict__ out)
{
    __shared__ float qs[64][32];    // qf tile [a][tok]
    __shared__ float Sms[64][64];   // Sm[h]   [a][f]
    __shared__ float svs[64];
    int t = threadIdx.x;
    int cx = blockIdx.x;
    int h = blockIdx.y;
    int n0 = cx * 32;

    const float* gq = ws + OFF_QF + (size_t)h*64*4096;
    #pragma unroll
    for (int i = 0; i < 8; ++i) {
        int idx = i*256 + t;            // 0..2047
        qs[idx >> 5][idx & 31] = gq[(size_t)(idx >> 5)*4096 + n0 + (idx & 31)];
    }
    const float* Smg = ws + OFF_SM + (size_t)h*4096;
    #pragma unroll
    for (int i = 0; i < 16; ++i) { int idx = i*256 + t; Sms[idx >> 6][idx & 63] = Smg[idx]; }
    if (t < 64) svs[t] = ws[OFF_SV + h*64 + t];
    __syncthreads();

    int e2 = (t >> 3) * 2;          // feat pair
    int n4 = (t & 7) * 4;           // token quad
    float acc[2][4];
    float den[4] = {0.f, 0.f, 0.f, 0.f};
    #pragma unroll
    for (int i = 0; i < 2; ++i)
        #pragma unroll
        for (int j = 0; j < 4; ++j) acc[i][j] = 0.f;
    #pragma unroll 4
    for (int a = 0; a < 64; ++a) {
        float4 qv4 = *(const float4*)&qs[a][n4];
        float qv[4] = {qv4.x, qv4.y, qv4.z, qv4.w};
        float sm0 = Sms[a][e2], sm1 = Sms[a][e2 + 1];
        float sva = svs[a];
        #pragma unroll
        for (int nj = 0; nj < 4; ++nj) {
            den[nj] = fmaf(qv[nj], sva, den[nj]);
            acc[0][nj] = fmaf(sm0, qv[nj], acc[0][nj]);
            acc[1][nj] = fmaf(sm1, qv[nj], acc[1][nj]);
        }
    }
    float r[4];
    #pragma unroll
    for (int nj = 0; nj < 4; ++nj) r[nj] = 1.f / (den[nj] + EPS_F);
    #pragma unroll
    for (int ei = 0; ei < 2; ++ei)
        *(float4*)&out[(size_t)(h*64 + e2 + ei)*4096 + n0 + n4] =
            make_float4(acc[ei][0]*r[0], acc[ei][1]*r[1], acc[ei][2]*r[2], acc[ei][3]*r[3]);
}

extern "C" void kernel_launch(void* const* d_in, const int* in_sizes, int n_in,
                              void* d_out, int out_size, void* d_ws, size_t ws_size,
                              hipStream_t stream) {
    const float* x   = (const float*)d_in[0];
    const float* Wq  = (const float*)d_in[1];
    const float* Wk  = (const float*)d_in[2];
    const float* Wv  = (const float*)d_in[3];
    const float* bv  = (const float*)d_in[4];
    const float* Wmq = (const float*)d_in[5];
    const float* bmq = (const float*)d_in[6];
    const float* Wmk = (const float*)d_in[7];
    const float* bmk = (const float*)d_in[8];
    const float* Wmv = (const float*)d_in[9];
    const float* bmv = (const float*)d_in[10];
    float* out = (float*)d_out;
    float* ws  = (float*)d_ws;

    k_pre<<<4738, 256, 0, stream>>>(x, Wq, Wk, Wv, bv, Wmq, Wmk, Wmv, bmv, ws);
    k_fused<<<dim3(128, 4), 512, 0, stream>>>(bmk, bmq, Wmv, ws);
    k_out<<<dim3(128, 8), 256, 0, stream>>>(ws, out);
}

// Round 10
// 127.636 us; speedup vs baseline: 1.4634x; 1.4634x over previous
//
#include <hip/hip_runtime.h>
#include <math.h>

#define EPS_F 1e-6f

typedef __attribute__((ext_vector_type(8))) short bf16x8;
typedef __attribute__((ext_vector_type(4))) float f32x4;

// ---- workspace layout (float offsets) ----
#define OFF_BV  0                            // folded v bias [256]
#define OFF_VC  (OFF_BV + 256)               // dwconv output [256][4096]
#define OFF_PS  (OFF_VC + 256*4096)          // partial Sm [8 h][128 chunk][64][64]
#define OFF_PSV (OFF_PS + 8*128*4096)        // partial sv [8 h][128 chunk][64]
#define OFF_SM  (OFF_PSV + 8*128*64)         // Sm [8][64*64] (atomic accum)
#define OFF_SV  (OFF_SM + 8*4096)            // sv [8][64]   (atomic accum)
#define OFF_QF  (OFF_SV + 512)               // qf [512 row=h*64+a][4096 n] fp32
#define OFF_WQH (OFF_QF + 512*4096)          // folded Wq hi bf16 [256][256] (ushort)
#define OFF_WQL (OFF_WQH + 32768)
#define OFF_WKH (OFF_WQL + 32768)
#define OFF_WKL (OFF_WKH + 32768)
#define OFF_XTH (OFF_WKL + 32768)            // X^T hi bf16 [4096 tok][256 c] (ushort)
#define OFF_XTL (OFF_XTH + 524288)

__device__ __forceinline__ void split_bf16(float v, unsigned short& h, unsigned short& l) {
    unsigned int b = __float_as_uint(v);
    h = (unsigned short)(b >> 16);
    float fh = __uint_as_float(b & 0xFFFF0000u);
    l = (unsigned short)(__float_as_uint(v - fh) >> 16);
}

// Prologue, 4738 blocks x 256 threads, full parallelism per job:
//   b <  4096: dwconv, 1 output/thread (c = b>>4, n = (b&15)*256+t)
//   b <  4352: weight fold (row b-4096)
//   b <  4608: X transpose/split (tile b-4352)
//   b <  4738: zero Sm/sv accumulators (for k_reduce atomics)
__global__ __launch_bounds__(256) void k_pre(
    const float* __restrict__ x,
    const float* __restrict__ Wq, const float* __restrict__ Wk,
    const float* __restrict__ Wv, const float* __restrict__ bv,
    const float* __restrict__ Wmq, const float* __restrict__ Wmk,
    const float* __restrict__ Wmv, const float* __restrict__ bmv,
    float* __restrict__ ws)
{
    __shared__ float Ts[64][65];
    int b = blockIdx.x, t = threadIdx.x;
    if (b < 4096) {
        int c = b >> 4;
        int n = (b & 15) * 256 + t;
        int z = n >> 8, y = (n >> 4) & 15, xx = n & 15;
        const float* xc = x + c * 4096;
        const float* wc = Wv + c * 27;
        float acc = 0.f;
        #pragma unroll
        for (int kz = 0; kz < 3; ++kz) {
            int zz = z + kz - 1;
            if (zz < 0 || zz > 15) continue;
            #pragma unroll
            for (int ky = 0; ky < 3; ++ky) {
                int yy = y + ky - 1;
                if (yy < 0 || yy > 15) continue;
                #pragma unroll
                for (int kx = 0; kx < 3; ++kx) {
                    int xv = xx + kx - 1;
                    if (xv < 0 || xv > 15) continue;
                    acc = fmaf(wc[(kz*3 + ky)*3 + kx], xc[(zz << 8) + (yy << 4) + xv], acc);
                }
            }
        }
        ws[OFF_VC + (size_t)c*4096 + n] = acc;
    } else if (b < 4352) {
        int row = b - 4096, c = t;
        int h = row >> 6, e = row & 63;
        float aq = 0.f, ak = 0.f;
        for (int d = 0; d < 64; ++d) {
            float mq = Wmq[e*64 + d];
            float mk = Wmk[e*64 + d];
            int src = (h*64 + d)*256 + c;
            aq = fmaf(mq, Wq[src], aq);
            ak = fmaf(mk, Wk[src], ak);
        }
        unsigned short hh, ll;
        unsigned short* WQH = (unsigned short*)(ws + OFF_WQH);
        unsigned short* WQL = (unsigned short*)(ws + OFF_WQL);
        unsigned short* WKH = (unsigned short*)(ws + OFF_WKH);
        unsigned short* WKL = (unsigned short*)(ws + OFF_WKL);
        split_bf16(aq, hh, ll); WQH[row*256 + c] = hh; WQL[row*256 + c] = ll;
        split_bf16(ak, hh, ll); WKH[row*256 + c] = hh; WKL[row*256 + c] = ll;
        if (c == 0) {
            float av = 0.f;
            for (int d = 0; d < 64; ++d) av = fmaf(Wmv[e*64 + d], bv[h*64 + d], av);
            ws[OFF_BV + row] = av + bmv[e];
        }
    } else if (b < 4608) {
        int bx = b - 4352;
        int tx = bx & 63, cy = bx >> 6;
        int lr = t >> 6, lc2 = t & 63;
        #pragma unroll
        for (int i = 0; i < 16; ++i) {
            int row = lr*16 + i;
            Ts[row][lc2] = x[(size_t)(cy*64 + row)*4096 + tx*64 + lc2];
        }
        __syncthreads();
        int tok = t >> 2, c16 = (t & 3) * 16;
        unsigned int hw[8], lw[8];
        #pragma unroll
        for (int j = 0; j < 8; ++j) {
            float v0 = Ts[c16 + 2*j][tok], v1 = Ts[c16 + 2*j + 1][tok];
            unsigned int b0 = __float_as_uint(v0), b1 = __float_as_uint(v1);
            hw[j] = (b0 >> 16) | (b1 & 0xFFFF0000u);
            float f0 = __uint_as_float(b0 & 0xFFFF0000u);
            float f1 = __uint_as_float(b1 & 0xFFFF0000u);
            lw[j] = (__float_as_uint(v0 - f0) >> 16) | (__float_as_uint(v1 - f1) & 0xFFFF0000u);
        }
        unsigned short* XH = (unsigned short*)(ws + OFF_XTH);
        unsigned short* XL = (unsigned short*)(ws + OFF_XTL);
        size_t base = (size_t)(tx*64 + tok)*256 + cy*64 + c16;
        uint4 H0 = {hw[0], hw[1], hw[2], hw[3]}, H1 = {hw[4], hw[5], hw[6], hw[7]};
        uint4 L0 = {lw[0], lw[1], lw[2], lw[3]}, L1 = {lw[4], lw[5], lw[6], lw[7]};
        *(uint4*)(XH + base) = H0;  *(uint4*)(XH + base + 8) = H1;
        *(uint4*)(XL + base) = L0;  *(uint4*)(XL + base + 8) = L1;
    } else {
        int idx = (b - 4608)*256 + t;        // 0..33279
        if (idx < 32768) ws[OFF_SM + idx] = 0.f;
        else             ws[OFF_SV + idx - 32768] = 0.f;
    }
}

// 512 threads / 8 waves, 32-token chunks, grid (128,4) = 512 blocks.
// LDS trimmed to exactly 40 KB (phase-1 staging footprint) -> 4 blocks/CU.
// Waves: kq=w>>2 (K/Q), mh=w&1 (token 16-half), nh=(w>>1)&1 (feat 32-half).
__global__ __launch_bounds__(512, 4) void k_fused(
    const float* __restrict__ bmk, const float* __restrict__ bmq,
    const float* __restrict__ Wmv, float* __restrict__ ws)
{
    __shared__ float smem[10240];   // 40 KB
    unsigned short* su = (unsigned short*)smem;

    int t = threadIdx.x;
    int chunk = blockIdx.x;       // 0..127
    int hb = blockIdx.y;          // 0..3
    int n0 = chunk * 32;
    int w = t >> 6, lane = t & 63;
    int kq = w >> 2;              // 0 = K waves, 1 = Q waves
    int wi = w & 3;
    int mh = wi & 1, nh = wi >> 1;
    int l15 = lane & 15, l4 = lane >> 4;
    bool isQ = (t >= 256);
    int tl = t & 255;

    const unsigned short* XH  = (const unsigned short*)(ws + OFF_XTH);
    const unsigned short* XL  = (const unsigned short*)(ws + OFF_XTL);
    const unsigned short* WKHp = (const unsigned short*)(ws + OFF_WKH);
    const unsigned short* WKLp = (const unsigned short*)(ws + OFF_WKL);
    const unsigned short* WQHp = (const unsigned short*)(ws + OFF_WQH);
    const unsigned short* WQLp = (const unsigned short*)(ws + OFF_WQL);

    f32x4 acc[2];
    acc[0] = (f32x4){0.f, 0.f, 0.f, 0.f};
    acc[1] = (f32x4){0.f, 0.f, 0.f, 0.f};
    float accV[2][4];
    #pragma unroll
    for (int i = 0; i < 2; ++i)
        #pragma unroll
        for (int j = 0; j < 4; ++j) accV[i][j] = 0.f;

    // ---- phase 1: K & Q projection GEMMs via MFMA, 4 slabs of K=64 ----
    // LDS: X hi/lo 2 x 2048 ushort [0..8KB); W 4 bufs x 4096 ushort [8KB..40KB)
    for (int cs = 0; cs < 4; ++cs) {
        int c0 = cs * 64;
        {
            int s = t & 7;
            int xb = t >> 8;                      // 0=hi 1=lo
            int r5 = (t >> 3) & 31;
            const unsigned short* XSrc = xb ? XL : XH;
            unsigned short* xd = su + xb*2048 + r5*64 + (((s) ^ (r5 & 7)) << 3);
            *(uint4*)xd = *(const uint4*)(XSrc + (size_t)(n0 + r5)*256 + c0 + s*8);
            int r6 = (t >> 3) & 63;
            size_t wo = (size_t)(hb*64 + r6)*256 + c0 + s*8;
            unsigned short* wd0 = su + 4096 + r6*64 + (((s) ^ (r6 & 7)) << 3);
            *(uint4*)(wd0)          = *(const uint4*)(WKHp + wo);
            *(uint4*)(wd0 + 4096)   = *(const uint4*)(WKLp + wo);
            *(uint4*)(wd0 + 8192)   = *(const uint4*)(WQHp + wo);
            *(uint4*)(wd0 + 12288)  = *(const uint4*)(WQLp + wo);
        }
        __syncthreads();
        const unsigned short* Xh = su;
        const unsigned short* Xl = su + 2048;
        const unsigned short* Wh = su + 4096 + kq*8192;
        const unsigned short* Wl = Wh + 4096;
        #pragma unroll
        for (int ks = 0; ks < 2; ++ks) {
            int ar = mh*16 + l15;
            int aoff = ar*64 + (((ks*4 + l4) ^ (ar & 7)) << 3);
            bf16x8 ah = *(const bf16x8*)(Xh + aoff);
            bf16x8 al = *(const bf16x8*)(Xl + aoff);
            #pragma unroll
            for (int nt = 0; nt < 2; ++nt) {
                int br = nh*32 + nt*16 + l15;
                int boff = br*64 + (((ks*4 + l4) ^ (br & 7)) << 3);
                bf16x8 bh = *(const bf16x8*)(Wh + boff);
                bf16x8 bl = *(const bf16x8*)(Wl + boff);
                acc[nt] = __builtin_amdgcn_mfma_f32_16x16x32_bf16(ah, bh, acc[nt], 0, 0, 0);
                acc[nt] = __builtin_amdgcn_mfma_f32_16x16x32_bf16(al, bh, acc[nt], 0, 0, 0);
                acc[nt] = __builtin_amdgcn_mfma_f32_16x16x32_bf16(ah, bl, acc[nt], 0, 0, 0);
            }
        }
        __syncthreads();
    }

    // ---- K waves stage V tiles: Vs[64 d][32 tok] @0, Wmv_s[64][68] @2048 ----
    float* Vs = smem;
    float* Wms = smem + 2048;
    if (!isQ) {
        const float* vcb = ws + OFF_VC + (size_t)hb*64*4096;
        #pragma unroll
        for (int i = 0; i < 8; ++i) {
            int idx = i*256 + tl;           // 0..2047
            int row = idx >> 5, col = idx & 31;
            Vs[row*32 + col] = vcb[(size_t)row*4096 + n0 + col];
        }
        #pragma unroll
        for (int i = 0; i < 16; ++i) { int idx = i*256 + tl; Wms[(idx & 63)*68 + (idx >> 6)] = Wmv[idx]; }
    }
    __syncthreads();

    // ---- V-projection GEMM (K waves, scalar, K=64), tile [2 tok][4 e] ----
    int n2 = (tl >> 4) * 2;
    int e4 = (tl & 15) * 4;
    if (!isQ) {
        #pragma unroll 4
        for (int d = 0; d < 64; ++d) {
            float x0 = Vs[d*32 + n2], x1 = Vs[d*32 + n2 + 1];
            float4 wv4 = *(const float4*)&Wms[d*68 + e4];
            float wv[4] = {wv4.x, wv4.y, wv4.z, wv4.w};
            #pragma unroll
            for (int jj = 0; jj < 4; ++jj) {
                accV[0][jj] = fmaf(x0, wv[jj], accV[0][jj]);
                accV[1][jj] = fmaf(x1, wv[jj], accV[1][jj]);
            }
        }
    }
    __syncthreads();

    // ---- phase 2: K waves write kf (MFMA frags) and vf (scalar) ----
    float* kfp = smem;          // [32][64]
    float* kfm = smem + 2048;
    float* vfp = smem + 4096;
    float* vfm = smem + 6144;
    if (!isQ) {
        float bk0 = bmk[nh*32 + l15], bk1 = bmk[nh*32 + 16 + l15];
        #pragma unroll
        for (int nt = 0; nt < 2; ++nt) {
            float bkv = nt ? bk1 : bk0;
            int feat = nh*32 + nt*16 + l15;
            #pragma unroll
            for (int r = 0; r < 4; ++r) {
                int tok = mh*16 + l4*4 + r;
                float v = acc[nt][r] + bkv;
                kfp[tok*64 + feat] = __expf(v);
                kfm[tok*64 + feat] = __expf(-v);
            }
        }
        float bvv[4];
        #pragma unroll
        for (int j = 0; j < 4; ++j) bvv[j] = ws[OFF_BV + hb*64 + e4 + j];
        #pragma unroll
        for (int ii = 0; ii < 2; ++ii) {
            float pv[4], mv[4];
            #pragma unroll
            for (int jj = 0; jj < 4; ++jj) {
                float bb = accV[ii][jj] + bvv[jj];
                pv[jj] = __expf(bb);  mv[jj] = __expf(-bb);
            }
            *(float4*)&vfp[(n2 + ii)*64 + e4] = make_float4(pv[0], pv[1], pv[2], pv[3]);
            *(float4*)&vfm[(n2 + ii)*64 + e4] = make_float4(mv[0], mv[1], mv[2], mv[3]);
        }
    }
    __syncthreads();

    // ---- phase 3: outer products over 16 tokens per group ----
    float aSp[4][4], aSm[4][4], svp[4], svm[4];
    #pragma unroll
    for (int i = 0; i < 4; ++i) {
        svp[i] = 0.f; svm[i] = 0.f;
        #pragma unroll
        for (int j = 0; j < 4; ++j) { aSp[i][j] = 0.f; aSm[i][j] = 0.f; }
    }
    int a4 = (tl & 15) * 4, f4 = (tl >> 4) * 4;
    int nb = isQ ? 16 : 0;
    #pragma unroll 2
    for (int nn = 0; nn < 16; ++nn) {
        int n = nb + nn;
        float4 kp4 = *(const float4*)&kfp[n*64 + a4];
        float4 km4 = *(const float4*)&kfm[n*64 + a4];
        float4 vp4 = *(const float4*)&vfp[n*64 + f4];
        float4 vm4 = *(const float4*)&vfm[n*64 + f4];
        float kp[4] = {kp4.x, kp4.y, kp4.z, kp4.w};
        float km[4] = {km4.x, km4.y, km4.z, km4.w};
        float vp[4] = {vp4.x, vp4.y, vp4.z, vp4.w};
        float vm[4] = {vm4.x, vm4.y, vm4.z, vm4.w};
        #pragma unroll
        for (int ai = 0; ai < 4; ++ai) {
            svp[ai] += kp[ai];  svm[ai] += km[ai];
            #pragma unroll
            for (int fi = 0; fi < 4; ++fi) {
                aSp[ai][fi] = fmaf(kp[ai], vp[fi], aSp[ai][fi]);
                aSm[ai][fi] = fmaf(km[ai], vm[fi], aSm[ai][fi]);
            }
        }
    }
    __syncthreads();

    // ---- exchange: Q dumps partials, K adds and writes PS/PSV ----
    if (isQ) {
        #pragma unroll
        for (int i = 0; i < 4; ++i)
            #pragma unroll
            for (int j = 0; j < 4; ++j) {
                smem[(i*4 + j)*256 + tl]      = aSp[i][j];
                smem[(16 + i*4 + j)*256 + tl] = aSm[i][j];
            }
        if (tl < 16) {
            #pragma unroll
            for (int i = 0; i < 4; ++i) {
                smem[8192 + i*16 + tl]      = svp[i];
                smem[8192 + 64 + i*16 + tl] = svm[i];
            }
        }
    }
    __syncthreads();
    if (!isQ) {
        #pragma unroll
        for (int i = 0; i < 4; ++i)
            #pragma unroll
            for (int j = 0; j < 4; ++j) {
                aSp[i][j] += smem[(i*4 + j)*256 + tl];
                aSm[i][j] += smem[(16 + i*4 + j)*256 + tl];
            }
        float* pSp = ws + OFF_PS + (size_t)(hb*128 + chunk)*4096;
        float* pSm = ws + OFF_PS + (size_t)((hb + 4)*128 + chunk)*4096;
        #pragma unroll
        for (int ai = 0; ai < 4; ++ai) {
            *(float4*)&pSp[(a4 + ai)*64 + f4] = make_float4(aSp[ai][0], aSp[ai][1], aSp[ai][2], aSp[ai][3]);
            *(float4*)&pSm[(a4 + ai)*64 + f4] = make_float4(aSm[ai][0], aSm[ai][1], aSm[ai][2], aSm[ai][3]);
        }
        if (tl < 16) {
            #pragma unroll
            for (int i = 0; i < 4; ++i) {
                svp[i] += smem[8192 + i*16 + tl];
                svm[i] += smem[8192 + 64 + i*16 + tl];
            }
            float* pvp = ws + OFF_PSV + (size_t)(hb*128 + chunk)*64;
            float* pvm = ws + OFF_PSV + (size_t)((hb + 4)*128 + chunk)*64;
            *(float4*)&pvp[a4] = make_float4(svp[0], svp[1], svp[2], svp[3]);
            *(float4*)&pvm[a4] = make_float4(svm[0], svm[1], svm[2], svm[3]);
        }
    }
    __syncthreads();

    // ---- Q waves: exp(+-q) -> LDS transpose qT[feat][tok] (stride 36) ----
    float* qTp = smem;              // 64*36
    float* qTm = smem + 2304;
    if (isQ) {
        float bq0 = bmq[nh*32 + l15], bq1 = bmq[nh*32 + 16 + l15];
        #pragma unroll
        for (int nt = 0; nt < 2; ++nt) {
            float bqv = nt ? bq1 : bq0;
            int feat = nh*32 + nt*16 + l15;
            #pragma unroll
            for (int r = 0; r < 4; ++r) {
                int tok = mh*16 + l4*4 + r;
                float v = acc[nt][r] + bqv;
                qTp[feat*36 + tok] = __expf(v);
                qTm[feat*36 + tok] = __expf(-v);
            }
        }
    }
    __syncthreads();
    // ---- all threads: copy qT -> global qf (feature-major layout) ----
    float* gq = ws + OFF_QF;
    #pragma unroll
    for (int j = 0; j < 2; ++j) {
        int un = t + 512*j;               // 0..1023
        int s = un >> 9;
        int rem = un & 511;
        int feat = rem >> 3, t4 = (rem & 7) * 4;
        const float* src = (s ? &qTm[feat*36 + t4] : &qTp[feat*36 + t4]);
        float4 v = *(const float4*)src;
        *(float4*)&gq[(size_t)((hb + 4*s)*64 + feat)*4096 + n0 + t4] = v;
    }
}

// Partial reduction: each thread sums 32 of the 128 chunk-partials and
// atomicAdds into the (pre-zeroed) Sm/sv. 521 blocks -> ~8 waves/CU.
__global__ __launch_bounds__(256) void k_reduce(float* __restrict__ ws)
{
    int tid = blockIdx.x*256 + threadIdx.x;      // 0..133375
    if (tid < 131072) {
        int part = tid >> 15;                     // 0..3
        int o = tid & 32767;                      // output idx
        int h = o >> 12, r = o & 4095;
        float s = 0.f;
        #pragma unroll 8
        for (int c = 0; c < 32; ++c)
            s += ws[OFF_PS + (size_t)(h*128 + part*32 + c)*4096 + r];
        atomicAdd(&ws[OFF_SM + o], s);
    } else if (tid < 131072 + 2048) {
        int j = tid - 131072;
        int part = j >> 9;
        int o = j & 511;
        int h = o >> 6, e = o & 63;
        float s = 0.f;
        #pragma unroll 8
        for (int c = 0; c < 32; ++c)
            s += ws[OFF_PSV + (size_t)(h*128 + part*32 + c)*64 + e];
        atomicAdd(&ws[OFF_SV + o], s);
    }
}

// Per (h 0..7, chunk32 0..127): out = (qf.Sm)/(qf.sv+eps).
// 24.5 KB LDS -> 6 blocks/CU with __launch_bounds__(256, 6).
__global__ __launch_bounds__(256, 6) void k_out(
    const float* __restrict__ ws, float* __restrict__ out)
{
    __shared__ float qs[64][32];    // qf tile [a][tok]
    __shared__ float Sms[64][64];   // Sm[h]   [a][f]
    __shared__ float svs[64];
    int t = threadIdx.x;
    int cx = blockIdx.x;
    int h = blockIdx.y;
    int n0 = cx * 32;

    const float* gq = ws + OFF_QF + (size_t)h*64*4096;
    #pragma unroll
    for (int i = 0; i < 8; ++i) {
        int idx = i*256 + t;            // 0..2047
        qs[idx >> 5][idx & 31] = gq[(size_t)(idx >> 5)*4096 + n0 + (idx & 31)];
    }
    const float* Smg = ws + OFF_SM + (size_t)h*4096;
    #pragma unroll
    for (int i = 0; i < 16; ++i) { int idx = i*256 + t; Sms[idx >> 6][idx & 63] = Smg[idx]; }
    if (t < 64) svs[t] = ws[OFF_SV + h*64 + t];
    __syncthreads();

    int e2 = (t >> 3) * 2;          // feat pair
    int n4 = (t & 7) * 4;           // token quad
    float acc[2][4];
    float den[4] = {0.f, 0.f, 0.f, 0.f};
    #pragma unroll
    for (int i = 0; i < 2; ++i)
        #pragma unroll
        for (int j = 0; j < 4; ++j) acc[i][j] = 0.f;
    #pragma unroll 4
    for (int a = 0; a < 64; ++a) {
        float4 qv4 = *(const float4*)&qs[a][n4];
        float qv[4] = {qv4.x, qv4.y, qv4.z, qv4.w};
        float sm0 = Sms[a][e2], sm1 = Sms[a][e2 + 1];
        float sva = svs[a];
        #pragma unroll
        for (int nj = 0; nj < 4; ++nj) {
            den[nj] = fmaf(qv[nj], sva, den[nj]);
            acc[0][nj] = fmaf(sm0, qv[nj], acc[0][nj]);
            acc[1][nj] = fmaf(sm1, qv[nj], acc[1][nj]);
        }
    }
    float r[4];
    #pragma unroll
    for (int nj = 0; nj < 4; ++nj) r[nj] = 1.f / (den[nj] + EPS_F);
    #pragma unroll
    for (int ei = 0; ei < 2; ++ei)
        *(float4*)&out[(size_t)(h*64 + e2 + ei)*4096 + n0 + n4] =
            make_float4(acc[ei][0]*r[0], acc[ei][1]*r[1], acc[ei][2]*r[2], acc[ei][3]*r[3]);
}

extern "C" void kernel_launch(void* const* d_in, const int* in_sizes, int n_in,
                              void* d_out, int out_size, void* d_ws, size_t ws_size,
                              hipStream_t stream) {
    const float* x   = (const float*)d_in[0];
    const float* Wq  = (const float*)d_in[1];
    const float* Wk  = (const float*)d_in[2];
    const float* Wv  = (const float*)d_in[3];
    const float* bv  = (const float*)d_in[4];
    const float* Wmq = (const float*)d_in[5];
    const float* bmq = (const float*)d_in[6];
    const float* Wmk = (const float*)d_in[7];
    const float* bmk = (const float*)d_in[8];
    const float* Wmv = (const float*)d_in[9];
    const float* bmv = (const float*)d_in[10];
    float* out = (float*)d_out;
    float* ws  = (float*)d_ws;

    k_pre<<<4738, 256, 0, stream>>>(x, Wq, Wk, Wv, bv, Wmq, Wmk, Wmv, bmv, ws);
    k_fused<<<dim3(128, 4), 512, 0, stream>>>(bmk, bmq, Wmv, ws);
    k_reduce<<<521, 256, 0, stream>>>(ws);
    k_out<<<dim3(128, 8), 256, 0, stream>>>(ws, out);
}